// Round 6
// baseline (234.177 us; speedup 1.0000x reference)
//
#include <hip/hip_runtime.h>
#include <hip/hip_bf16.h>

// Problem constants (B,N,D,H from reference)
#define Bc 64
#define Nc 512
#define Dc 1024
#define Hc 2048
#define Mc (Bc * Nc)          // 32768 rows

// GEMM tiling: 256x256 tile, BK=64, 8 waves (2M x 4N), double-buffered LDS
#define BM 256
#define BH 256
#define BK 64
#define KTILES (Dc / BK)      // 16
#define MTILES (Mc / BM)      // 128
#define HTILES (Hc / BH)      // 8
#define NSLICE (HTILES * 4)   // 32 score slices (ht x wave-column)

typedef __attribute__((ext_vector_type(8))) short bf16x8;
typedef __attribute__((ext_vector_type(4))) float f32x4;
typedef __attribute__((ext_vector_type(16))) float f32x16;

__device__ __forceinline__ unsigned short f2bf(float f) {
    unsigned u = __float_as_uint(f);
    u += 0x7FFFu + ((u >> 16) & 1u);   // RNE
    return (unsigned short)(u >> 16);
}

__device__ __forceinline__ void stage16(const void* g, void* l) {
    __builtin_amdgcn_global_load_lds(
        (const __attribute__((address_space(1))) unsigned int*)g,
        (__attribute__((address_space(3))) unsigned int*)l,
        16, 0, 0);
}

// ---------------- Kernel A: cast x -> bf16, energy = sigmoid(rowsum(x^2)) ----
__global__ void __launch_bounds__(256) cast_energy(
    const float* __restrict__ x, unsigned short* __restrict__ xb,
    float* __restrict__ energy)
{
    const int row = blockIdx.x;            // 0..Mc-1
    const int tid = threadIdx.x;           // 256 threads, 4 f32 each
    const float4 v = ((const float4*)(x + (size_t)row * Dc))[tid];
    ushort4 o;
    o.x = f2bf(v.x); o.y = f2bf(v.y); o.z = f2bf(v.z); o.w = f2bf(v.w);
    ((ushort4*)(xb + (size_t)row * Dc))[tid] = o;

    float s = v.x * v.x + v.y * v.y + v.z * v.z + v.w * v.w;
    #pragma unroll
    for (int m = 1; m < 64; m <<= 1) s += __shfl_xor(s, m);
    __shared__ float ws[4];
    if ((tid & 63) == 0) ws[tid >> 6] = s;
    __syncthreads();
    if (tid == 0) {
        float t = ws[0] + ws[1] + ws[2] + ws[3];
        energy[row] = 1.0f / (1.0f + expf(-t));
    }
}

// ---------------- Kernel B: cast W1 -> bf16 ---------------------------------
__global__ void __launch_bounds__(256) cast_w1(
    const float* __restrict__ w1, unsigned short* __restrict__ w1b)
{
    const size_t i = (size_t)blockIdx.x * blockDim.x + threadIdx.x; // x4 elems
    const float4 v = ((const float4*)w1)[i];
    ushort4 o;
    o.x = f2bf(v.x); o.y = f2bf(v.y); o.z = f2bf(v.z); o.w = f2bf(v.w);
    ((ushort4*)w1b)[i] = o;
}

// ---------------- Kernel C: fused bf16 GEMM + relu + W2-reduce --------------
// 256x256 tile, 8 waves, dbuf LDS, prefetch-1 staging, 32x32x16 MFMA.
// score_part[(ht*4 + wc)*Mc + row] = sum over slice's 64 h of
//     relu(x.W1[h] + b1[h]) * W2[h]
__global__ void __launch_bounds__(512, 2) fused_gemm_score(
    const unsigned short* __restrict__ xb,    // [Mc][Dc] bf16 bits
    const unsigned short* __restrict__ w1b,   // [Hc][Dc] bf16 bits
    const float* __restrict__ b1,             // [Hc]
    const float* __restrict__ w2,             // [Hc]
    float* __restrict__ score_part)           // [NSLICE][Mc]
{
    // dynamic LDS: [2 buf][A 32KB | B 32KB] = 128 KB
    extern __shared__ __attribute__((aligned(16))) char lds[];

    const int tid   = threadIdx.x;
    const int lane  = tid & 63;
    const int wid   = tid >> 6;               // 0..7
    const int wr    = wid >> 2;               // 0..1  (m half: 128 rows)
    const int wc    = wid & 3;                // 0..3  (h quarter: 64 cols)
    const int l31   = lane & 31;
    const int lhalf = lane >> 5;              // 0..1

    // bijective XCD swizzle (1024 % 8 == 0): ht fastest within an XCD so the
    // 8 blocks sharing one x-tile run adjacently; W1 (4MB) stays L2-resident.
    const int b  = blockIdx.x;
    const int wg = (b & 7) * (MTILES * HTILES / 8) + (b >> 3);
    const int mt = wg >> 3;                   // 0..127
    const int ht = wg & 7;                    // 0..7
    const int m0 = mt * BM;
    const int h0 = ht * BH;

    // epilogue coefficients prefetch (h-col = lane&31 within each 32-block)
    float b1v[2], w2v[2];
    #pragma unroll
    for (int nb = 0; nb < 2; ++nb) {
        const int h = h0 + wc * 64 + nb * 32 + l31;
        b1v[nb] = b1[h];
        w2v[nb] = w2[h];
    }

    // staging geometry (rule #21: linear LDS dest + pre-swizzled src col)
    const int srow    = tid >> 3;             // 0..63
    const int scol_sw = ((((tid & 7) * 16) ^ ((srow & 7) << 4)) >> 1); // elems

#define LDSA(bf) (lds + (bf) * 65536)
#define LDSB(bf) (lds + (bf) * 65536 + 32768)

    // running global base pointers for staging (advance by BK per tile)
    const unsigned short* gA = xb  + (size_t)(m0 + srow) * Dc + scol_sw;
    const unsigned short* gB = w1b + (size_t)(h0 + srow) * Dc + scol_sw;

    // swizzled ds_read byte offsets: row = l31 (+32*mb), chunk (ks,half)
    const int swz  = (lane & 7) << 4;
    int offk[4];
    #pragma unroll
    for (int ks = 0; ks < 4; ++ks) offk[ks] = (ks * 32 + lhalf * 16) ^ swz;
    const int arowb = (wr * 128 + l31) * 128; // byte row base within A panel
    const int browb = (wc * 64 + l31) * 128;  // byte row base within B panel

// fragment reads: one 32-row m-block of A (4 x b128), all B (8 x b128)
#define RD_A32(dst, bf, mb) { \
    _Pragma("unroll") for (int ks = 0; ks < 4; ++ks) \
        dst[ks] = *(const bf16x8*)(LDSA(bf) + arowb + (mb) * 4096 + offk[ks]); }
#define RD_B32(bf) { \
    _Pragma("unroll") for (int nb = 0; nb < 2; ++nb) \
    _Pragma("unroll") for (int ks = 0; ks < 4; ++ks) \
        bfr[nb][ks] = *(const bf16x8*)(LDSB(bf) + browb + (nb) * 4096 + offk[ks]); }

// one 32-row m-block x both n-blocks x K=64 : 8 MFMA (32x32x16)
#define MM32(av, mb) { \
    __builtin_amdgcn_s_setprio(1); \
    _Pragma("unroll") for (int ks = 0; ks < 4; ++ks) \
    _Pragma("unroll") for (int nb = 0; nb < 2; ++nb) \
        acc[mb][nb] = __builtin_amdgcn_mfma_f32_32x32x16_bf16( \
            av[ks], bfr[nb][ks], acc[mb][nb], 0, 0, 0); \
    __builtin_amdgcn_s_setprio(0); }

    bf16x8 bfr[2][4];       // B fragments for whole tile (32 regs)
    bf16x8 aP[4], aQ[4];    // two alternating A m-block buffers
    f32x16 acc[4][2];
    #pragma unroll
    for (int m = 0; m < 4; ++m)
        #pragma unroll
        for (int n = 0; n < 2; ++n) acc[m][n] = (f32x16)(0.0f);

    // prologue: stage K-tile 0 into buf 0
    #pragma unroll
    for (int c = 0; c < 4; ++c) {
        stage16(gA + (size_t)c * 64 * Dc, LDSA(0) + c * 8192 + tid * 16);
        stage16(gB + (size_t)c * 64 * Dc, LDSB(0) + c * 8192 + tid * 16);
    }
    gA += BK; gB += BK;
    __syncthreads();   // compiler drains vmcnt(0) here

    int cur = 0;
    for (int kt = 0; kt < KTILES; ++kt) {
        // issue next-tile staging first: in flight across this tile's compute
        if (kt + 1 < KTILES) {
            const int nb = cur ^ 1;
            #pragma unroll
            for (int c = 0; c < 4; ++c) {
                stage16(gA + (size_t)c * 64 * Dc, LDSA(nb) + c * 8192 + tid * 16);
                stage16(gB + (size_t)c * 64 * Dc, LDSB(nb) + c * 8192 + tid * 16);
            }
            gA += BK; gB += BK;
        }

        // software-pipelined: B + first two A m-blocks, then roll
        RD_B32(cur);
        RD_A32(aP, cur, 0);
        RD_A32(aQ, cur, 1);
        MM32(aP, 0);
        RD_A32(aP, cur, 2);
        MM32(aQ, 1);
        RD_A32(aQ, cur, 3);
        MM32(aP, 2);
        MM32(aQ, 3);

        __syncthreads();   // next buffer staged; all reads of cur done
        cur ^= 1;
    }

    // fold: +b1, relu, *W2 -> per-row partials [mb][reg]
    float sp[4][16];
    #pragma unroll
    for (int m = 0; m < 4; ++m)
        #pragma unroll
        for (int r = 0; r < 16; ++r) sp[m][r] = 0.0f;
    #pragma unroll
    for (int m = 0; m < 4; ++m)
        #pragma unroll
        for (int nb = 0; nb < 2; ++nb)
            #pragma unroll
            for (int r = 0; r < 16; ++r) {
                float v = acc[m][nb][r] + b1v[nb];
                v = v > 0.0f ? v : 0.0f;
                sp[m][r] += v * w2v[nb];
            }

    // reduce over the 32 h-columns held by lanes (bits 0..4 of lane)
    #pragma unroll
    for (int m = 0; m < 4; ++m)
        #pragma unroll
        for (int r = 0; r < 16; ++r) {
            float v = sp[m][r];
            v += __shfl_xor(v, 1);
            v += __shfl_xor(v, 2);
            v += __shfl_xor(v, 4);
            v += __shfl_xor(v, 8);
            v += __shfl_xor(v, 16);
            sp[m][r] = v;
        }

    // C/D layout 32x32: row = (r&3) + 8*(r>>2) + 4*lhalf, col = l31
    if (l31 == 0) {
        const size_t base = (size_t)(ht * 4 + wc) * Mc;
        #pragma unroll
        for (int m = 0; m < 4; ++m)
            #pragma unroll
            for (int r = 0; r < 16; ++r) {
                const int row = m0 + wr * 128 + m * 32 +
                                (r & 3) + 8 * (r >> 2) + 4 * lhalf;
                score_part[base + row] = sp[m][r];
            }
    }
}

// ---------------- Kernel D: finalize + write filter matrix ------------------
__global__ void __launch_bounds__(256) finalize(
    const float* __restrict__ score_part, const float* __restrict__ energy,
    const float* __restrict__ b2, float* __restrict__ out)
{
    const int row = blockIdx.x * 2 + (threadIdx.x >> 7);  // 0..Mc-1
    const int t   = threadIdx.x & 127;                    // 128 thr per row

    float s = b2[0];
    #pragma unroll
    for (int g = 0; g < NSLICE; ++g) s += score_part[(size_t)g * Mc + row];
    const float attn = (1.0f / (1.0f + expf(-s))) * energy[row];

    const int n = row & (Nc - 1);
    float4 z = make_float4(0.0f, 0.0f, 0.0f, 0.0f);
    if (t == (n >> 2)) ((float*)&z)[n & 3] = attn;
    ((float4*)(out + (size_t)row * Nc))[t] = z;
    if (t == 0) out[(size_t)Bc * Nc * Nc + row] = attn;
}

// ---------------- Host launcher ---------------------------------------------
extern "C" void kernel_launch(void* const* d_in, const int* in_sizes, int n_in,
                              void* d_out, int out_size, void* d_ws, size_t ws_size,
                              hipStream_t stream) {
    const float* x  = (const float*)d_in[0];
    const float* W1 = (const float*)d_in[1];
    const float* b1 = (const float*)d_in[2];
    const float* W2 = (const float*)d_in[3];
    const float* b2 = (const float*)d_in[4];
    float* out = (float*)d_out;

    const size_t xb_bytes = (size_t)Mc * Dc * 2;     // 64 MB
    const size_t w1_bytes = (size_t)Hc * Dc * 2;     // 4 MB
    const size_t e_bytes  = (size_t)Mc * 4;          // 128 KB
    const size_t s_bytes  = (size_t)NSLICE * Mc * 4; // 4 MB

    char* ws = (char*)d_ws;
    unsigned short* xb;
    if (ws_size >= xb_bytes + w1_bytes + e_bytes + s_bytes + 256) {
        xb = (unsigned short*)ws; ws += xb_bytes;
    } else {
        // use the filter region of d_out (67 MB >= 64 MB) as bf16-x scratch;
        // finalize() fully overwrites it afterwards.
        xb = (unsigned short*)d_out;
    }
    unsigned short* w1b = (unsigned short*)ws; ws += w1_bytes;
    float* energy = (float*)ws; ws += e_bytes;
    float* score  = (float*)ws; ws += s_bytes;

    cast_energy<<<Mc, 256, 0, stream>>>(x, xb, energy);
    cast_w1<<<(Hc * Dc / 4) / 256, 256, 0, stream>>>(W1, w1b);
    fused_gemm_score<<<MTILES * HTILES, 512, 131072, stream>>>(xb, w1b, b1, W2, score);
    finalize<<<Mc / 2, 256, 0, stream>>>(score, energy, b2, out);
}

// Round 7
// 211.461 us; speedup vs baseline: 1.1074x; 1.1074x over previous
//
#include <hip/hip_runtime.h>
#include <hip/hip_bf16.h>

// Problem constants (B,N,D,H from reference)
#define Bc 64
#define Nc 512
#define Dc 1024
#define Hc 2048
#define Mc (Bc * Nc)          // 32768 rows

// GEMM tiling: 256x256 tile, BK=64, 8 waves (2M x 4N), 8-phase dbuf schedule
#define BM 256
#define BH 256
#define BK 64
#define KTILES (Dc / BK)      // 16
#define MTILES (Mc / BM)      // 128
#define HTILES (Hc / BH)      // 8
#define NSLICE (HTILES * 4)   // 32 score slices (ht x wave-column)

typedef __attribute__((ext_vector_type(8))) short bf16x8;
typedef __attribute__((ext_vector_type(4))) float f32x4;

__device__ __forceinline__ unsigned short f2bf(float f) {
    unsigned u = __float_as_uint(f);
    u += 0x7FFFu + ((u >> 16) & 1u);   // RNE
    return (unsigned short)(u >> 16);
}

__device__ __forceinline__ void stage16(const void* g, void* l) {
    __builtin_amdgcn_global_load_lds(
        (const __attribute__((address_space(1))) unsigned int*)g,
        (__attribute__((address_space(3))) unsigned int*)l,
        16, 0, 0);
}

// ---------------- Kernel A: cast x -> bf16, energy = sigmoid(rowsum(x^2)) ----
__global__ void __launch_bounds__(256) cast_energy(
    const float* __restrict__ x, unsigned short* __restrict__ xb,
    float* __restrict__ energy)
{
    const int row = blockIdx.x;            // 0..Mc-1
    const int tid = threadIdx.x;           // 256 threads, 4 f32 each
    const float4 v = ((const float4*)(x + (size_t)row * Dc))[tid];
    ushort4 o;
    o.x = f2bf(v.x); o.y = f2bf(v.y); o.z = f2bf(v.z); o.w = f2bf(v.w);
    ((ushort4*)(xb + (size_t)row * Dc))[tid] = o;

    float s = v.x * v.x + v.y * v.y + v.z * v.z + v.w * v.w;
    #pragma unroll
    for (int m = 1; m < 64; m <<= 1) s += __shfl_xor(s, m);
    __shared__ float ws[4];
    if ((tid & 63) == 0) ws[tid >> 6] = s;
    __syncthreads();
    if (tid == 0) {
        float t = ws[0] + ws[1] + ws[2] + ws[3];
        energy[row] = 1.0f / (1.0f + expf(-t));
    }
}

// ---------------- Kernel B: cast W1 -> bf16 ---------------------------------
__global__ void __launch_bounds__(256) cast_w1(
    const float* __restrict__ w1, unsigned short* __restrict__ w1b)
{
    const size_t i = (size_t)blockIdx.x * blockDim.x + threadIdx.x; // x4 elems
    const float4 v = ((const float4*)w1)[i];
    ushort4 o;
    o.x = f2bf(v.x); o.y = f2bf(v.y); o.z = f2bf(v.z); o.w = f2bf(v.w);
    ((ushort4*)w1b)[i] = o;
}

// ---------------- Kernel C: fused bf16 GEMM + relu + W2-reduce --------------
// 256x256 tile, 8 waves, 16x16x32 MFMA, 8-phase schedule: uniform 1
// staging-half-tile per phase, counted vmcnt(4) at ph3/ph7 only, peeled
// final iteration (no wrap staging). T2 swizzle + T5 setprio.
// score_part[(ht*4 + wc)*Mc + row] = sum over slice's 64 h of
//     relu(x.W1[h] + b1[h]) * W2[h]
__global__ void __launch_bounds__(512, 2) fused_gemm_score(
    const unsigned short* __restrict__ xb,    // [Mc][Dc] bf16 bits
    const unsigned short* __restrict__ w1b,   // [Hc][Dc] bf16 bits
    const float* __restrict__ b1,             // [Hc]
    const float* __restrict__ w2,             // [Hc]
    float* __restrict__ score_part)           // [NSLICE][Mc]
{
    // [2 buf][A 32KB | B 32KB] = 128 KB dynamic LDS
    extern __shared__ __attribute__((aligned(16))) char lds[];

    const int tid  = threadIdx.x;
    const int lane = tid & 63;
    const int wid  = tid >> 6;                // 0..7
    const int wr   = wid >> 2;                // 0..1  (m half: 128 rows)
    const int wc   = wid & 3;                 // 0..3  (h quarter: 64 cols)
    const int l15  = lane & 15;
    const int l4   = lane >> 4;               // 0..3

    // bijective XCD swizzle (1024 % 8 == 0): ht fastest within an XCD.
    const int b  = blockIdx.x;
    const int wg = (b & 7) * (MTILES * HTILES / 8) + (b >> 3);
    const int mt = wg >> 3;                   // 0..127
    const int ht = wg & 7;                    // 0..7
    const int m0 = mt * BM;
    const int h0 = ht * BH;

    // epilogue coefficients prefetch
    float b1v[4], w2v[4];
    #pragma unroll
    for (int n = 0; n < 4; ++n) {
        const int h = h0 + wc * 64 + n * 16 + l15;
        b1v[n] = b1[h];
        w2v[n] = w2[h];
    }

    // staging geometry (rule #21: linear LDS dest + pre-swizzled src col)
    const int srow    = tid >> 3;             // 0..63
    const int scol_sw = ((((tid & 7) * 16) ^ ((srow & 7) << 4)) >> 1); // elems

    // swizzled ds_read byte offsets
    const int swz   = (lane & 7) << 4;
    const int offk0 = (l4 * 16) ^ swz;
    const int offk1 = (64 + l4 * 16) ^ swz;

#define LDSA(bf) (lds + (bf) * 65536)
#define LDSB(bf) (lds + (bf) * 65536 + 32768)

// stage one staging-half (rows h*128..h*128+127) of K-tile kt into buf bf
#define STG_AH(bf, h, kt) { \
    const unsigned short* _g = xb + (size_t)(m0 + (h) * 128 + srow) * Dc + (kt) * BK + scol_sw; \
    char* _d = LDSA(bf) + (h) * 16384 + tid * 16; \
    stage16(_g, _d); \
    stage16(_g + (size_t)64 * Dc, _d + 8192); }
#define STG_BH(bf, h, kt) { \
    const unsigned short* _g = w1b + (size_t)(h0 + (h) * 128 + srow) * Dc + (kt) * BK + scol_sw; \
    char* _d = LDSB(bf) + (h) * 16384 + tid * 16; \
    stage16(_g, _d); \
    stage16(_g + (size_t)64 * Dc, _d + 8192); }

// fragment reads (8 b128 for an A m-half, 4 b128 for a B n-half)
#define RD_A(dst, bf, mh) { \
    _Pragma("unroll") for (int mf = 0; mf < 4; ++mf) { \
        dst[mf][0] = *(const bf16x8*)(LDSA(bf) + (wr * 128 + (mh) * 64 + mf * 16 + l15) * 128 + offk0); \
        dst[mf][1] = *(const bf16x8*)(LDSA(bf) + (wr * 128 + (mh) * 64 + mf * 16 + l15) * 128 + offk1); } }
#define RD_B(dst, bf, nh) { \
    _Pragma("unroll") for (int nf = 0; nf < 2; ++nf) { \
        dst[nf][0] = *(const bf16x8*)(LDSB(bf) + (wc * 64 + (nh) * 32 + nf * 16 + l15) * 128 + offk0); \
        dst[nf][1] = *(const bf16x8*)(LDSB(bf) + (wc * 64 + (nh) * 32 + nf * 16 + l15) * 128 + offk1); } }

// one C-quadrant (m-half x n-half) x K=64 : 16 MFMA
#define MM(av, bv, mh, nh) { \
    __builtin_amdgcn_s_setprio(1); \
    _Pragma("unroll") for (int mf = 0; mf < 4; ++mf) \
    _Pragma("unroll") for (int nf = 0; nf < 2; ++nf) { \
        acc[(mh)*4+mf][(nh)*2+nf] = __builtin_amdgcn_mfma_f32_16x16x32_bf16( \
            av[mf][0], bv[nf][0], acc[(mh)*4+mf][(nh)*2+nf], 0, 0, 0); \
        acc[(mh)*4+mf][(nh)*2+nf] = __builtin_amdgcn_mfma_f32_16x16x32_bf16( \
            av[mf][1], bv[nf][1], acc[(mh)*4+mf][(nh)*2+nf], 0, 0, 0); } \
    __builtin_amdgcn_s_setprio(0); }

#define BAR   __builtin_amdgcn_s_barrier()
#define LGKM0 { asm volatile("s_waitcnt lgkmcnt(0)" ::: "memory"); \
                __builtin_amdgcn_sched_barrier(0); }
#define VM4   asm volatile("s_waitcnt vmcnt(4)" ::: "memory")
#define VM0   asm volatile("s_waitcnt vmcnt(0)" ::: "memory")

    bf16x8 a0[4][2], a1[4][2], b0[2][2], b1f[2][2];
    f32x4  acc[8][4];
    #pragma unroll
    for (int m = 0; m < 8; ++m)
        #pragma unroll
        for (int n = 0; n < 4; ++n) acc[m][n] = (f32x4)(0.0f);

    // prologue: buf0 = tile0 (4 halves, oldest), then buf1.Bs0/Bs1 = tile1.
    // vmcnt(4) drains exactly tile0's 8 loads.
    STG_BH(0, 0, 0); STG_BH(0, 1, 0); STG_AH(0, 0, 0); STG_AH(0, 1, 0);
    STG_BH(1, 0, 1); STG_BH(1, 1, 1);
    VM4; BAR;

    for (int t = 0; t < KTILES / 2 - 1; ++t) {   // t = 0..6
        const int k1 = 2 * t + 1, k2 = 2 * t + 2, k3 = 2 * t + 3;
        // ph0: compute buf0 q(m0,n0); stage buf1.As0 (tile k1)
        RD_A(a0, 0, 0); RD_B(b0, 0, 0); STG_AH(1, 0, k1);
        BAR; LGKM0; MM(a0, b0, 0, 0); BAR;
        // ph1: q(m0,n1); stage buf1.As1 (k1)
        RD_B(b1f, 0, 1); STG_AH(1, 1, k1);
        BAR; LGKM0; MM(a0, b1f, 0, 1); BAR;
        // ph2: q(m1,n0); stage buf0.Bs0 (k2)
        RD_A(a1, 0, 1); STG_BH(0, 0, k2);
        BAR; LGKM0; MM(a1, b0, 1, 0); BAR;
        // ph3: q(m1,n1); stage buf0.Bs1 (k2); counted wait -> buf1 ready
        STG_BH(0, 1, k2);
        BAR; MM(a1, b1f, 1, 1); VM4; BAR;
        // ph4: compute buf1 q(m0,n0); stage buf0.As0 (k2)
        RD_A(a0, 1, 0); RD_B(b0, 1, 0); STG_AH(0, 0, k2);
        BAR; LGKM0; MM(a0, b0, 0, 0); BAR;
        // ph5: q(m0,n1); stage buf0.As1 (k2)
        RD_B(b1f, 1, 1); STG_AH(0, 1, k2);
        BAR; LGKM0; MM(a0, b1f, 0, 1); BAR;
        // ph6: q(m1,n0); stage buf1.Bs0 (k3)
        RD_A(a1, 1, 1); STG_BH(1, 0, k3);
        BAR; LGKM0; MM(a1, b0, 1, 0); BAR;
        // ph7: q(m1,n1); stage buf1.Bs1 (k3); counted wait -> buf0 ready
        STG_BH(1, 1, k3);
        BAR; MM(a1, b1f, 1, 1); VM4; BAR;
    }

    // peeled final iteration: tiles 14 (buf0), 15 (buf1); only tile 15's
    // A-halves still need staging (ph0/ph1); no further prefetch.
    RD_A(a0, 0, 0); RD_B(b0, 0, 0); STG_AH(1, 0, 15);
    BAR; LGKM0; MM(a0, b0, 0, 0); BAR;
    RD_B(b1f, 0, 1); STG_AH(1, 1, 15);
    BAR; LGKM0; MM(a0, b1f, 0, 1); BAR;
    RD_A(a1, 0, 1);
    BAR; LGKM0; MM(a1, b0, 1, 0); BAR;
    BAR; MM(a1, b1f, 1, 1); VM0; BAR;
    RD_A(a0, 1, 0); RD_B(b0, 1, 0);
    BAR; LGKM0; MM(a0, b0, 0, 0); BAR;
    RD_B(b1f, 1, 1);
    BAR; LGKM0; MM(a0, b1f, 0, 1); BAR;
    RD_A(a1, 1, 1);
    BAR; LGKM0; MM(a1, b0, 1, 0); BAR;
    LGKM0; MM(a1, b1f, 1, 1);

    // fold: +b1, relu, *W2 -> per-row partials, then reduce over l15 columns
    float sp[8][4];
    #pragma unroll
    for (int m = 0; m < 8; ++m)
        #pragma unroll
        for (int j = 0; j < 4; ++j) sp[m][j] = 0.0f;
    #pragma unroll
    for (int n = 0; n < 4; ++n)
        #pragma unroll
        for (int m = 0; m < 8; ++m)
            #pragma unroll
            for (int j = 0; j < 4; ++j) {
                float v = acc[m][n][j] + b1v[n];
                v = v > 0.0f ? v : 0.0f;
                sp[m][j] += v * w2v[n];
            }

    #pragma unroll
    for (int m = 0; m < 8; ++m)
        #pragma unroll
        for (int j = 0; j < 4; ++j) {
            float v = sp[m][j];
            v += __shfl_xor(v, 1);
            v += __shfl_xor(v, 2);
            v += __shfl_xor(v, 4);
            v += __shfl_xor(v, 8);
            sp[m][j] = v;
        }

    if (l15 == 0) {
        const size_t base = (size_t)(ht * 4 + wc) * Mc;
        #pragma unroll
        for (int m = 0; m < 8; ++m)
            #pragma unroll
            for (int j = 0; j < 4; ++j) {
                const int row = m0 + wr * 128 + m * 16 + l4 * 4 + j;
                score_part[base + row] = sp[m][j];
            }
    }
}

// ---------------- Kernel D: finalize + write filter matrix ------------------
__global__ void __launch_bounds__(256) finalize(
    const float* __restrict__ score_part, const float* __restrict__ energy,
    const float* __restrict__ b2, float* __restrict__ out)
{
    const int row = blockIdx.x * 2 + (threadIdx.x >> 7);  // 0..Mc-1
    const int t   = threadIdx.x & 127;                    // 128 thr per row

    float s = b2[0];
    #pragma unroll
    for (int g = 0; g < NSLICE; ++g) s += score_part[(size_t)g * Mc + row];
    const float attn = (1.0f / (1.0f + expf(-s))) * energy[row];

    const int n = row & (Nc - 1);
    float4 z = make_float4(0.0f, 0.0f, 0.0f, 0.0f);
    if (t == (n >> 2)) ((float*)&z)[n & 3] = attn;
    ((float4*)(out + (size_t)row * Nc))[t] = z;
    if (t == 0) out[(size_t)Bc * Nc * Nc + row] = attn;
}

// ---------------- Host launcher ---------------------------------------------
extern "C" void kernel_launch(void* const* d_in, const int* in_sizes, int n_in,
                              void* d_out, int out_size, void* d_ws, size_t ws_size,
                              hipStream_t stream) {
    const float* x  = (const float*)d_in[0];
    const float* W1 = (const float*)d_in[1];
    const float* b1 = (const float*)d_in[2];
    const float* W2 = (const float*)d_in[3];
    const float* b2 = (const float*)d_in[4];
    float* out = (float*)d_out;

    const size_t xb_bytes = (size_t)Mc * Dc * 2;     // 64 MB
    const size_t w1_bytes = (size_t)Hc * Dc * 2;     // 4 MB
    const size_t e_bytes  = (size_t)Mc * 4;          // 128 KB
    const size_t s_bytes  = (size_t)NSLICE * Mc * 4; // 4 MB

    char* ws = (char*)d_ws;
    unsigned short* xb;
    if (ws_size >= xb_bytes + w1_bytes + e_bytes + s_bytes + 256) {
        xb = (unsigned short*)ws; ws += xb_bytes;
    } else {
        // use the filter region of d_out (67 MB >= 64 MB) as bf16-x scratch;
        // finalize() fully overwrites it afterwards.
        xb = (unsigned short*)d_out;
    }
    unsigned short* w1b = (unsigned short*)ws; ws += w1_bytes;
    float* energy = (float*)ws; ws += e_bytes;
    float* score  = (float*)ws; ws += s_bytes;

    cast_energy<<<Mc, 256, 0, stream>>>(x, xb, energy);
    cast_w1<<<(Hc * Dc / 4) / 256, 256, 0, stream>>>(W1, w1b);
    fused_gemm_score<<<MTILES * HTILES, 512, 131072, stream>>>(xb, w1b, b1, W2, score);
    finalize<<<Mc / 2, 256, 0, stream>>>(score, energy, b2, out);
}

// Round 8
// 207.407 us; speedup vs baseline: 1.1291x; 1.0195x over previous
//
#include <hip/hip_runtime.h>
#include <hip/hip_bf16.h>

// Problem constants (B,N,D,H from reference)
#define Bc 64
#define Nc 512
#define Dc 1024
#define Hc 2048
#define Mc (Bc * Nc)          // 32768 rows

// GEMM tiling: 256x256 tile, BK=64, 8 waves (2M x 4N), double-buffered LDS
#define BM 256
#define BH 256
#define BK 64
#define KTILES (Dc / BK)      // 16
#define MTILES (Mc / BM)      // 128
#define HTILES (Hc / BH)      // 8
#define NSLICE (HTILES * 4)   // 32 score slices (ht x wave-column)
#define ITEMS 4               // work items per persistent block

typedef __attribute__((ext_vector_type(8))) short bf16x8;
typedef __attribute__((ext_vector_type(4))) float f32x4;

__device__ __forceinline__ unsigned short f2bf(float f) {
    unsigned u = __float_as_uint(f);
    u += 0x7FFFu + ((u >> 16) & 1u);   // RNE
    return (unsigned short)(u >> 16);
}

__device__ __forceinline__ void stage16(const void* g, void* l) {
    __builtin_amdgcn_global_load_lds(
        (const __attribute__((address_space(1))) unsigned int*)g,
        (__attribute__((address_space(3))) unsigned int*)l,
        16, 0, 0);
}

// ------- Kernel A: fused {cast x + energy} | {cast W1} (one launch) ---------
__global__ void __launch_bounds__(256) cast_fused(
    const float* __restrict__ x, const float* __restrict__ w1,
    unsigned short* __restrict__ xb, unsigned short* __restrict__ w1b,
    float* __restrict__ energy)
{
    const int tid = threadIdx.x;
    if (blockIdx.x < Mc) {
        const int row = blockIdx.x;            // 0..Mc-1
        const float4 v = ((const float4*)(x + (size_t)row * Dc))[tid];
        ushort4 o;
        o.x = f2bf(v.x); o.y = f2bf(v.y); o.z = f2bf(v.z); o.w = f2bf(v.w);
        ((ushort4*)(xb + (size_t)row * Dc))[tid] = o;

        float s = v.x * v.x + v.y * v.y + v.z * v.z + v.w * v.w;
        #pragma unroll
        for (int m = 1; m < 64; m <<= 1) s += __shfl_xor(s, m);
        __shared__ float ws[4];
        if ((tid & 63) == 0) ws[tid >> 6] = s;
        __syncthreads();
        if (tid == 0) {
            float t = ws[0] + ws[1] + ws[2] + ws[3];
            energy[row] = 1.0f / (1.0f + expf(-t));
        }
    } else {
        const size_t i = (size_t)(blockIdx.x - Mc) * 256 + tid; // x4 elems
        const float4 v = ((const float4*)w1)[i];
        ushort4 o;
        o.x = f2bf(v.x); o.y = f2bf(v.y); o.z = f2bf(v.z); o.w = f2bf(v.w);
        ((ushort4*)w1b)[i] = o;
    }
}

// ---------------- Kernel C: fused bf16 GEMM + relu + W2-reduce --------------
// Persistent: 256 blocks (1/CU), each runs ITEMS=4 m-tiles at a fixed h-tile.
// Per item: 256x256 tile, 8 waves, dbuf LDS, prefetch-1 staging (R5 core).
// Next item's tile-0 is staged during the current item's last K-tile, so only
// the very first item pays a prologue stall.
// score_part[(ht*4 + wc)*Mc + row] = sum over slice's 64 h of
//     relu(x.W1[h] + b1[h]) * W2[h]
__global__ void __launch_bounds__(512, 2) fused_gemm_score(
    const unsigned short* __restrict__ xb,    // [Mc][Dc] bf16 bits
    const unsigned short* __restrict__ w1b,   // [Hc][Dc] bf16 bits
    const float* __restrict__ b1,             // [Hc]
    const float* __restrict__ w2,             // [Hc]
    float* __restrict__ score_part)           // [NSLICE][Mc]
{
    // dynamic LDS: [2 buf][2 mat][256*64] bf16 = 128 KB
    extern __shared__ __attribute__((aligned(16))) unsigned short lds[];

    const int tid  = threadIdx.x;
    const int lane = tid & 63;
    const int wid  = tid >> 6;                // 0..7
    const int wr   = wid >> 2;                // 0..1  (m half: 128 rows)
    const int wc   = wid & 3;                 // 0..3  (h quarter: 64 cols)
    const int l15  = lane & 15;
    const int l4   = lane >> 4;               // 0..3

    // persistent work mapping: xcd = b&7, q = b>>3 (0..31).
    // item w: wg = xcd*128 + w*32 + q -> ht = q&7 (const), mt = xcd*16+w*4+(q>>3).
    // 8 blocks (same XCD, same mt-group, all ht) share each x-tile -> L2 hits;
    // W1 h-slice is L2-resident across the block's 4 items.
    const int bxcd = blockIdx.x & 7;
    const int q    = blockIdx.x >> 3;
    const int ht   = q & 7;
    const int mtb  = bxcd * 16 + (q >> 3);    // mt for item w = mtb + w*4
    const int h0   = ht * BH;

    // epilogue coefficients: once per block (ht fixed)
    float b1v[4], w2v[4];
    #pragma unroll
    for (int n = 0; n < 4; ++n) {
        const int h = h0 + wc * 64 + n * 16 + l15;
        b1v[n] = b1[h];
        w2v[n] = w2[h];
    }

    // staging geometry (rule #21: linear LDS dest + pre-swizzled src col)
    const int srow    = tid >> 3;             // 0..63
    const int scol_sw = ((((tid & 7) * 16) ^ ((srow & 7) << 4)) >> 1); // elems

    unsigned short* A0p = lds;                // [buf*32768 + mat*16384] elems
    #define LDSBUF(buf, mat) (A0p + (buf) * 32768 + (mat) * 16384)

    // swizzled ds_read byte offsets within a 128-byte row
    const int swz   = (l15 & 7) << 4;
    const int offk0 = ((l4 * 16) ^ swz);
    const int offk1 = ((64 + l4 * 16) ^ swz);
    const int arow  = (wr * 128 + l15) * 128; // byte row base within A
    const int brow  = (wc * 64 + l15) * 128;  // byte row base within B

// fragment reads (8 b128 for an A m-half, 4 b128 for a B n-half)
#define RD_A(dst, bf, mh) { \
    _Pragma("unroll") for (int mf = 0; mf < 4; ++mf) { \
        dst[mf][0] = *(const bf16x8*)((char*)LDSBUF(bf, 0) + arow + ((mh)*64 + mf*16) * 128 + offk0); \
        dst[mf][1] = *(const bf16x8*)((char*)LDSBUF(bf, 0) + arow + ((mh)*64 + mf*16) * 128 + offk1); } }
#define RD_B(dst, bf, nh) { \
    _Pragma("unroll") for (int nf = 0; nf < 2; ++nf) { \
        dst[nf][0] = *(const bf16x8*)((char*)LDSBUF(bf, 1) + brow + ((nh)*32 + nf*16) * 128 + offk0); \
        dst[nf][1] = *(const bf16x8*)((char*)LDSBUF(bf, 1) + brow + ((nh)*32 + nf*16) * 128 + offk1); } }

// one C-quadrant (m-half x n-half) x K=64 : 16 MFMA
#define MMQ(av, bv, mh, nh) { \
    __builtin_amdgcn_s_setprio(1); \
    _Pragma("unroll") for (int mf = 0; mf < 4; ++mf) \
    _Pragma("unroll") for (int nf = 0; nf < 2; ++nf) { \
        acc[(mh)*4+mf][(nh)*2+nf] = __builtin_amdgcn_mfma_f32_16x16x32_bf16( \
            av[mf][0], bv[nf][0], acc[(mh)*4+mf][(nh)*2+nf], 0, 0, 0); \
        acc[(mh)*4+mf][(nh)*2+nf] = __builtin_amdgcn_mfma_f32_16x16x32_bf16( \
            av[mf][1], bv[nf][1], acc[(mh)*4+mf][(nh)*2+nf], 0, 0, 0); } \
    __builtin_amdgcn_s_setprio(0); }

    const unsigned short* gBbase = w1b + (size_t)(h0 + srow) * Dc + scol_sw;

    // prologue: stage item 0's K-tile 0 into buf 0
    {
        const unsigned short* gA0 =
            xb + (size_t)(mtb * BM + srow) * Dc + scol_sw;
        #pragma unroll
        for (int c = 0; c < 4; ++c) {
            stage16(gA0 + (size_t)c * 64 * Dc,
                    ((char*)LDSBUF(0, 0)) + c * 8192 + tid * 16);
            stage16(gBbase + (size_t)c * 64 * Dc,
                    ((char*)LDSBUF(0, 1)) + c * 8192 + tid * 16);
        }
    }
    __syncthreads();   // compiler drains vmcnt(0) here

    int cur = 0;
    for (int w = 0; w < ITEMS; ++w) {
        const int mt = mtb + w * 4;
        const int m0 = mt * BM;

        // running staging pointers for this item (tile kt=1 first)
        const unsigned short* gA = xb + (size_t)(m0 + srow) * Dc + scol_sw + BK;
        const unsigned short* gB = gBbase + BK;

        f32x4 acc[8][4];
        #pragma unroll
        for (int m = 0; m < 8; ++m)
            #pragma unroll
            for (int n = 0; n < 4; ++n) acc[m][n] = (f32x4)(0.0f);

        for (int kt = 0; kt < KTILES; ++kt) {
            // issue staging first: in flight across this tile's compute
            const int nb = cur ^ 1;
            if (kt + 1 < KTILES) {
                #pragma unroll
                for (int c = 0; c < 4; ++c) {
                    stage16(gA + (size_t)c * 64 * Dc,
                            ((char*)LDSBUF(nb, 0)) + c * 8192 + tid * 16);
                    stage16(gB + (size_t)c * 64 * Dc,
                            ((char*)LDSBUF(nb, 1)) + c * 8192 + tid * 16);
                }
                gA += BK; gB += BK;
            } else if (w + 1 < ITEMS) {
                // stage NEXT item's tile 0 (same ht -> same B panel source)
                const unsigned short* gA2 =
                    xb + (size_t)((mt + 4) * BM + srow) * Dc + scol_sw;
                #pragma unroll
                for (int c = 0; c < 4; ++c) {
                    stage16(gA2 + (size_t)c * 64 * Dc,
                            ((char*)LDSBUF(nb, 0)) + c * 8192 + tid * 16);
                    stage16(gBbase + (size_t)c * 64 * Dc,
                            ((char*)LDSBUF(nb, 1)) + c * 8192 + tid * 16);
                }
            }

            bf16x8 a0[4][2], a1[4][2], b0[2][2], b1f[2][2];

            // software pipeline: reads for quadrant q+1 issued BEFORE MFMA(q)
            RD_A(a0, cur, 0); RD_B(b0, cur, 0);   // q0 operands
            RD_B(b1f, cur, 1);                    // q1 operand, under MM(q0)
            MMQ(a0, b0, 0, 0);
            RD_A(a1, cur, 1);                     // q2 operand, under MM(q1)
            MMQ(a0, b1f, 0, 1);
            MMQ(a1, b1f, 1, 1);
            MMQ(a1, b0, 1, 0);

            __syncthreads();   // next buffer staged; all reads of cur done
            cur ^= 1;
        }

        // epilogue: +b1, relu, *W2 -> per-row partials, reduce over l15 cols
        float sp[8][4];
        #pragma unroll
        for (int m = 0; m < 8; ++m)
            #pragma unroll
            for (int j = 0; j < 4; ++j) sp[m][j] = 0.0f;
        #pragma unroll
        for (int n = 0; n < 4; ++n)
            #pragma unroll
            for (int m = 0; m < 8; ++m)
                #pragma unroll
                for (int j = 0; j < 4; ++j) {
                    float v = acc[m][n][j] + b1v[n];
                    v = v > 0.0f ? v : 0.0f;
                    sp[m][j] += v * w2v[n];
                }

        #pragma unroll
        for (int m = 0; m < 8; ++m)
            #pragma unroll
            for (int j = 0; j < 4; ++j) {
                float v = sp[m][j];
                v += __shfl_xor(v, 1);
                v += __shfl_xor(v, 2);
                v += __shfl_xor(v, 4);
                v += __shfl_xor(v, 8);
                sp[m][j] = v;
            }

        if (l15 == 0) {
            const size_t base = (size_t)(ht * 4 + wc) * Mc;
            #pragma unroll
            for (int m = 0; m < 8; ++m)
                #pragma unroll
                for (int j = 0; j < 4; ++j) {
                    const int row = m0 + wr * 128 + m * 16 + l4 * 4 + j;
                    score_part[base + row] = sp[m][j];
                }
        }
    }
}

// ---------------- Kernel D: finalize + write filter matrix ------------------
__global__ void __launch_bounds__(256) finalize(
    const float* __restrict__ score_part, const float* __restrict__ energy,
    const float* __restrict__ b2, float* __restrict__ out)
{
    const int row = blockIdx.x * 2 + (threadIdx.x >> 7);  // 0..Mc-1
    const int t   = threadIdx.x & 127;                    // 128 thr per row

    float s = b2[0];
    #pragma unroll
    for (int g = 0; g < NSLICE; ++g) s += score_part[(size_t)g * Mc + row];
    const float attn = (1.0f / (1.0f + expf(-s))) * energy[row];

    const int n = row & (Nc - 1);
    float4 z = make_float4(0.0f, 0.0f, 0.0f, 0.0f);
    if (t == (n >> 2)) ((float*)&z)[n & 3] = attn;
    ((float4*)(out + (size_t)row * Nc))[t] = z;
    if (t == 0) out[(size_t)Bc * Nc * Nc + row] = attn;
}

// ---------------- Host launcher ---------------------------------------------
extern "C" void kernel_launch(void* const* d_in, const int* in_sizes, int n_in,
                              void* d_out, int out_size, void* d_ws, size_t ws_size,
                              hipStream_t stream) {
    const float* x  = (const float*)d_in[0];
    const float* W1 = (const float*)d_in[1];
    const float* b1 = (const float*)d_in[2];
    const float* W2 = (const float*)d_in[3];
    const float* b2 = (const float*)d_in[4];
    float* out = (float*)d_out;

    const size_t xb_bytes = (size_t)Mc * Dc * 2;     // 64 MB
    const size_t w1_bytes = (size_t)Hc * Dc * 2;     // 4 MB
    const size_t e_bytes  = (size_t)Mc * 4;          // 128 KB
    const size_t s_bytes  = (size_t)NSLICE * Mc * 4; // 4 MB

    char* ws = (char*)d_ws;
    unsigned short* xb;
    if (ws_size >= xb_bytes + w1_bytes + e_bytes + s_bytes + 256) {
        xb = (unsigned short*)ws; ws += xb_bytes;
    } else {
        // use the filter region of d_out (67 MB >= 64 MB) as bf16-x scratch;
        // finalize() fully overwrites it afterwards.
        xb = (unsigned short*)d_out;
    }
    unsigned short* w1b = (unsigned short*)ws; ws += w1_bytes;
    float* energy = (float*)ws; ws += e_bytes;
    float* score  = (float*)ws; ws += s_bytes;

    const int w1_blocks = (Hc * Dc / 4) / 256;       // 2048
    cast_fused<<<Mc + w1_blocks, 256, 0, stream>>>(x, W1, xb, w1b, energy);
    fused_gemm_score<<<256, 512, 131072, stream>>>(xb, w1b, b1, W2, score);
    finalize<<<Mc / 2, 256, 0, stream>>>(score, energy, b2, out);
}